// Round 1
// baseline (445.435 us; speedup 1.0000x reference)
//
#include <hip/hip_runtime.h>

#define TTOT 16384   // 4 * 4096 tokens
#define DDIM 2048
#define NEXP 64
#define KC   64      // K chunk staged in LDS
#define TPB  64      // tokens per block

// One block = 64 tokens x 64 experts. 4 waves/block; wave w owns expert
// quarter [16w, 16w+16). Each thread owns ONE token (its lane's token) and
// 16 experts -> 16 accumulators. W row segment is wave-uniform -> s_load
// (scalar pipe), x comes from LDS (1 b32 per 16 FMA, 2-way banks = free).
__global__ __launch_bounds__(256)
void moe_router(const float* __restrict__ x, const float* __restrict__ W,
                float* __restrict__ out)
{
    __shared__ float xs[TPB][KC + 1];   // +1 pad: 65-stride -> <=2-way bank aliasing
    const int tid  = threadIdx.x;
    const int lane = tid & 63;
    // force wave-uniform scalar so W loads become s_load_dwordx*
    const int wq   = __builtin_amdgcn_readfirstlane(tid >> 6);
    const int tokBase = blockIdx.x * TPB;

    double acc64[16];
#pragma unroll
    for (int i = 0; i < 16; ++i) acc64[i] = 0.0;

    const int sr = tid >> 4;          // staging row 0..15
    const int sc = (tid & 15) << 2;   // staging col (float4)

    for (int kb = 0; kb < DDIM; kb += KC) {
        __syncthreads();
#pragma unroll
        for (int rr = 0; rr < TPB; rr += 16) {
            const float4 v = *(const float4*)(x + (size_t)(tokBase + sr + rr) * DDIM + kb + sc);
            xs[sr + rr][sc + 0] = v.x;
            xs[sr + rr][sc + 1] = v.y;
            xs[sr + rr][sc + 2] = v.z;
            xs[sr + rr][sc + 3] = v.w;
        }
        __syncthreads();

        // fp32 within the 64-wide chunk, fp64 across chunks (accuracy: the
        // harness requires exact top-2 agreement with the np reference).
        float acc32[16];
#pragma unroll
        for (int i = 0; i < 16; ++i) acc32[i] = 0.0f;

        const float* Wp = W + (size_t)kb * NEXP + wq * 16;  // wave-uniform
#pragma unroll 4
        for (int d = 0; d < KC; ++d) {
            const float xv = xs[lane][d];
#pragma unroll
            for (int i = 0; i < 16; ++i)
                acc32[i] = fmaf(xv, Wp[d * NEXP + i], acc32[i]);
        }
#pragma unroll
        for (int i = 0; i < 16; ++i) acc64[i] += (double)acc32[i];
    }

    // gather logits [64 tok][64 exp] into LDS (reuse xs, same 65-stride)
    __syncthreads();
#pragma unroll
    for (int i = 0; i < 16; ++i)
        xs[lane][wq * 16 + i] = (float)acc64[i];
    __syncthreads();

    float* dispatch = out;
    float* probs    = out + (size_t)TTOT * NEXP;
    float* tkp      = out + (size_t)2 * TTOT * NEXP;
    float* tki      = tkp + (size_t)TTOT * 2;

    // each wave: softmax + top-2 for 16 tokens, lane = expert
    for (int tt = 0; tt < 16; ++tt) {
        const int t  = wq * 16 + tt;
        const int gt = tokBase + t;
        const float L = xs[t][lane];

        float m = L;
#pragma unroll
        for (int off = 32; off; off >>= 1) m = fmaxf(m, __shfl_xor(m, off, 64));
        const float p = expf(L - m);
        float s = p;
#pragma unroll
        for (int off = 32; off; off >>= 1) s += __shfl_xor(s, off, 64);
        const float prob = p / s;

        // top-1 (ties -> lowest index, matching lax.top_k)
        float v1 = prob; int i1 = lane;
#pragma unroll
        for (int off = 32; off; off >>= 1) {
            const float ov = __shfl_xor(v1, off, 64);
            const int   oi = __shfl_xor(i1, off, 64);
            if (ov > v1 || (ov == v1 && oi < i1)) { v1 = ov; i1 = oi; }
        }
        // top-2
        float v2 = (lane == i1) ? -1.0f : prob; int i2 = lane;
#pragma unroll
        for (int off = 32; off; off >>= 1) {
            const float ov = __shfl_xor(v2, off, 64);
            const int   oi = __shfl_xor(i2, off, 64);
            if (ov > v2 || (ov == v2 && oi < i2)) { v2 = ov; i2 = oi; }
        }

        probs[(size_t)gt * NEXP + lane]    = prob;
        dispatch[(size_t)gt * NEXP + lane] = (lane == i1 || lane == i2) ? 1.0f : 0.0f;
        if (lane == 0) {
            tkp[(size_t)gt * 2 + 0] = v1;
            tkp[(size_t)gt * 2 + 1] = v2;
            tki[(size_t)gt * 2 + 0] = (float)i1;
            tki[(size_t)gt * 2 + 1] = (float)i2;
        }
    }
}

extern "C" void kernel_launch(void* const* d_in, const int* in_sizes, int n_in,
                              void* d_out, int out_size, void* d_ws, size_t ws_size,
                              hipStream_t stream) {
    const float* x = (const float*)d_in[0];
    const float* W = (const float*)d_in[1];
    float* out = (float*)d_out;
    moe_router<<<TTOT / TPB, 256, 0, stream>>>(x, W, out);
}

// Round 2
// 398.176 us; speedup vs baseline: 1.1187x; 1.1187x over previous
//
#include <hip/hip_runtime.h>

#define TTOT 16384   // 4 * 4096 tokens
#define DDIM 2048
#define NEXP 64
#define KC   64      // K chunk staged in LDS
#define TPB  64      // tokens per block
#define EPT  8       // experts per thread  -> waves/CU = 64/EPT = 8 (2/SIMD)
#define PAD  68      // LDS row stride: 16B-aligned (ds_read_b128) + uniform banks

// Block = 512 threads (8 waves) = 64 tokens x 64 experts. Wave w owns experts
// [8w, 8w+8). Lane owns one token. W segment is wave-uniform -> s_load
// (scalar pipe); x staged once to LDS, read back as ds_read_b128.
__global__ __launch_bounds__(512)
void moe_router(const float* __restrict__ x, const float* __restrict__ W,
                float* __restrict__ out)
{
    __shared__ float xs[TPB][PAD];
    const int tid  = threadIdx.x;
    const int lane = tid & 63;
    const int wq   = __builtin_amdgcn_readfirstlane(tid >> 6);  // 0..7
    const int e0   = wq * EPT;
    const int tokBase = blockIdx.x * TPB;

    double acc64[EPT];
#pragma unroll
    for (int i = 0; i < EPT; ++i) acc64[i] = 0.0;

    // staging map: thread t -> row t>>3 (0..63), cols (t&7)*8 .. +8 (2 float4)
    const int sr = tid >> 3;
    const int sc = (tid & 7) << 3;

    for (int kb = 0; kb < DDIM; kb += KC) {
        __syncthreads();
        {
            const float* src = x + (size_t)(tokBase + sr) * DDIM + kb + sc;
            const float4 v0 = *(const float4*)(src + 0);
            const float4 v1 = *(const float4*)(src + 4);
            *(float4*)&xs[sr][sc + 0] = v0;
            *(float4*)&xs[sr][sc + 4] = v1;
        }
        __syncthreads();

        // fp32 within the 64-wide chunk, fp64 across chunks (top-2 must match
        // the np reference exactly; near-ties are the failure mode).
        float acc32[EPT];
#pragma unroll
        for (int i = 0; i < EPT; ++i) acc32[i] = 0.0f;

        const float* Wp = W + (size_t)kb * NEXP + e0;  // wave-uniform -> SGPR
#pragma unroll 4
        for (int d4 = 0; d4 < KC / 4; ++d4) {
            const float4 xv = *(const float4*)&xs[lane][d4 * 4];
            const float xvj[4] = {xv.x, xv.y, xv.z, xv.w};
#pragma unroll
            for (int j = 0; j < 4; ++j) {
                const float* Wr = Wp + (size_t)(d4 * 4 + j) * NEXP;
#pragma unroll
                for (int i = 0; i < EPT; ++i)
                    acc32[i] = fmaf(xvj[j], Wr[i], acc32[i]);
            }
        }
#pragma unroll
        for (int i = 0; i < EPT; ++i) acc64[i] += (double)acc32[i];
    }

    // gather logits [64 tok][64 exp] into LDS (reuse xs)
    __syncthreads();
#pragma unroll
    for (int i = 0; i < EPT; ++i)
        xs[lane][e0 + i] = (float)acc64[i];
    __syncthreads();

    float* dispatch = out;
    float* probs    = out + (size_t)TTOT * NEXP;
    float* tkp      = out + (size_t)2 * TTOT * NEXP;
    float* tki      = tkp + (size_t)TTOT * 2;

    // each wave: softmax + top-2 for 8 tokens, lane = expert
    for (int tt = 0; tt < TPB / 8; ++tt) {
        const int t  = wq * 8 + tt;
        const int gt = tokBase + t;
        const float L = xs[t][lane];

        float m = L;
#pragma unroll
        for (int off = 32; off; off >>= 1) m = fmaxf(m, __shfl_xor(m, off, 64));
        const float p = expf(L - m);
        float s = p;
#pragma unroll
        for (int off = 32; off; off >>= 1) s += __shfl_xor(s, off, 64);
        const float prob = p / s;

        // top-1 (ties -> lowest index, matching lax.top_k)
        float v1 = prob; int i1 = lane;
#pragma unroll
        for (int off = 32; off; off >>= 1) {
            const float ov = __shfl_xor(v1, off, 64);
            const int   oi = __shfl_xor(i1, off, 64);
            if (ov > v1 || (ov == v1 && oi < i1)) { v1 = ov; i1 = oi; }
        }
        // top-2
        float v2 = (lane == i1) ? -1.0f : prob; int i2 = lane;
#pragma unroll
        for (int off = 32; off; off >>= 1) {
            const float ov = __shfl_xor(v2, off, 64);
            const int   oi = __shfl_xor(i2, off, 64);
            if (ov > v2 || (ov == v2 && oi < i2)) { v2 = ov; i2 = oi; }
        }

        probs[(size_t)gt * NEXP + lane]    = prob;
        dispatch[(size_t)gt * NEXP + lane] = (lane == i1 || lane == i2) ? 1.0f : 0.0f;
        if (lane == 0) {
            tkp[(size_t)gt * 2 + 0] = v1;
            tkp[(size_t)gt * 2 + 1] = v2;
            tki[(size_t)gt * 2 + 0] = (float)i1;
            tki[(size_t)gt * 2 + 1] = (float)i2;
        }
    }
}

extern "C" void kernel_launch(void* const* d_in, const int* in_sizes, int n_in,
                              void* d_out, int out_size, void* d_ws, size_t ws_size,
                              hipStream_t stream) {
    const float* x = (const float*)d_in[0];
    const float* W = (const float*)d_in[1];
    float* out = (float*)d_out;
    moe_router<<<TTOT / TPB, 512, 0, stream>>>(x, W, out);
}

// Round 3
// 323.265 us; speedup vs baseline: 1.3779x; 1.2317x over previous
//
#include <hip/hip_runtime.h>

#define TTOT 16384   // 4 * 4096 tokens
#define DDIM 2048
#define NEXP 64
#define KC   32      // K chunk held in VGPRs (W) / streamed via s_load (x)
#define TPW  4       // tokens per wave
#define WPB  4       // waves per block -> 16 tokens/block, grid 1024, 16 waves/CU

// Transposed mapping: lane = expert (64 experts = 64 lanes), wave owns TPW
// tokens. W[d][lane] is per-lane & coalesced -> VGPR-resident per chunk
// (vmcnt). x[tok][d] is wave-uniform -> scalar s_load stream (lgkmcnt holds
// SMEM only -> pipelines). No LDS, no barriers, waves fully independent.
__global__ __launch_bounds__(256, 4)
void moe_router(const float* __restrict__ x, const float* __restrict__ W,
                float* __restrict__ out)
{
    const int lane = threadIdx.x & 63;
    const int wq   = __builtin_amdgcn_readfirstlane(threadIdx.x >> 6);
    const int tok0 = (blockIdx.x * WPB + wq) * TPW;

    const float* Wl  = W + lane;                 // lane's expert column
    const float* xr0 = x + (size_t)tok0 * DDIM;  // wave-uniform

    double acc64[TPW];
#pragma unroll
    for (int t = 0; t < TPW; ++t) acc64[t] = 0.0;

    for (int kb = 0; kb < DDIM; kb += KC) {
        // W chunk -> VGPRs (coalesced 256B per d, reused by TPW tokens)
        float w[KC];
#pragma unroll
        for (int j = 0; j < KC; ++j)
            w[j] = Wl[(size_t)(kb + j) * NEXP];

#pragma unroll
        for (int t = 0; t < TPW; ++t) {
            const float* xr = xr0 + (size_t)t * DDIM + kb;  // uniform -> s_load
            // fp32 within the chunk (2 independent chains to cover FMA
            // latency), fp64 across chunks: top-2 must match np exactly.
            float a0 = 0.0f, a1 = 0.0f;
#pragma unroll
            for (int j = 0; j < KC; j += 2) {
                a0 = fmaf(xr[j + 0], w[j + 0], a0);
                a1 = fmaf(xr[j + 1], w[j + 1], a1);
            }
            acc64[t] += (double)(a0 + a1);
        }
    }

    float* dispatch = out;
    float* probs    = out + (size_t)TTOT * NEXP;
    float* tkp      = out + (size_t)2 * TTOT * NEXP;
    float* tki      = tkp + (size_t)TTOT * 2;

    // logits already sit lane=expert: softmax + top-2 per token via shuffles
#pragma unroll
    for (int t = 0; t < TPW; ++t) {
        const int gt  = tok0 + t;
        const float L = (float)acc64[t];

        float m = L;
#pragma unroll
        for (int off = 32; off; off >>= 1) m = fmaxf(m, __shfl_xor(m, off, 64));
        const float p = expf(L - m);
        float s = p;
#pragma unroll
        for (int off = 32; off; off >>= 1) s += __shfl_xor(s, off, 64);
        const float prob = p / s;

        // top-1 (ties -> lowest index, matching lax.top_k / np)
        float v1 = prob; int i1 = lane;
#pragma unroll
        for (int off = 32; off; off >>= 1) {
            const float ov = __shfl_xor(v1, off, 64);
            const int   oi = __shfl_xor(i1, off, 64);
            if (ov > v1 || (ov == v1 && oi < i1)) { v1 = ov; i1 = oi; }
        }
        // top-2
        float v2 = (lane == i1) ? -1.0f : prob; int i2 = lane;
#pragma unroll
        for (int off = 32; off; off >>= 1) {
            const float ov = __shfl_xor(v2, off, 64);
            const int   oi = __shfl_xor(i2, off, 64);
            if (ov > v2 || (ov == v2 && oi < i2)) { v2 = ov; i2 = oi; }
        }

        probs[(size_t)gt * NEXP + lane]    = prob;
        dispatch[(size_t)gt * NEXP + lane] = (lane == i1 || lane == i2) ? 1.0f : 0.0f;
        if (lane == 0) {
            tkp[(size_t)gt * 2 + 0] = v1;
            tkp[(size_t)gt * 2 + 1] = v2;
            tki[(size_t)gt * 2 + 0] = (float)i1;
            tki[(size_t)gt * 2 + 1] = (float)i2;
        }
    }
}

extern "C" void kernel_launch(void* const* d_in, const int* in_sizes, int n_in,
                              void* d_out, int out_size, void* d_ws, size_t ws_size,
                              hipStream_t stream) {
    const float* x = (const float*)d_in[0];
    const float* W = (const float*)d_in[1];
    float* out = (float*)d_out;
    moe_router<<<TTOT / (TPW * WPB), 256, 0, stream>>>(x, W, out);
}